// Round 6
// baseline (260.400 us; speedup 1.0000x reference)
//
#include <hip/hip_runtime.h>

// FlexAttention: sliding-window (512) causal attention.
// B=2, H=16, L=2048, E=128, fp32 in/out, bf16 MFMA compute, fp32 accum.
// R5 (resubmit; infra failure last round): PV = R2's known-correct scalar
// V-gathers (sV[32][130]); KEEP reg-double-buffered staging (T14) and
// bijective XCD swizzle (T1). tr_read path removed pending a controlled
// single-variable experiment.

typedef __bf16 bf16_t;
typedef bf16_t bf16x8 __attribute__((ext_vector_type(8)));
typedef float f32x4 __attribute__((ext_vector_type(4)));

union FragU { bf16x8 v; unsigned short s[8]; };

__device__ __forceinline__ unsigned short f2bf(float f) {
    union { float f; unsigned u; } x; x.f = f;
    unsigned u = x.u;
    u += 0x7fffu + ((u >> 16) & 1u);   // RNE
    return (unsigned short)(u >> 16);
}

constexpr int B_ = 2, H_ = 16, Lq = 2048, E_ = 128, WIN = 512;
constexpr int QT = 64;     // q rows per block (4 waves x 16)
constexpr int KT = 32;     // keys per kv tile
constexpr int KSTR = 128;  // sK row stride (u16); XOR-swizzled within row
constexpr int VSTR = 130;  // sV row stride (u16); odd dword stride -> conflict-light gathers
constexpr int PSTR = 40;   // sP row stride (u16)

// (1/sqrt(128)) * log2(e); softmax done in exp2 domain
#define SCALE_LOG2E 0.1275174364f

extern "C" __global__ __launch_bounds__(256, 4)
void flexattn_kernel(const float* __restrict__ Q,
                     const float* __restrict__ K,
                     const float* __restrict__ V,
                     float* __restrict__ O)
{
    __shared__ unsigned short sK[KT * KSTR];   // row-major, XOR-swizzled
    __shared__ unsigned short sV[KT * VSTR];   // row-major, padded stride
    __shared__ unsigned short sP[4 * 16 * PSTR];

    const int tid  = threadIdx.x;
    const int w    = tid >> 6;     // wave 0..3
    const int lane = tid & 63;
    const int c    = lane & 15;    // col within MFMA tile
    const int g    = lane >> 4;    // 16-lane group 0..3

    // bijective XCD swizzle: XCD x owns bh in [4x, 4x+4), q-tiles in order
    const int bid = blockIdx.x;
    const int swz = (bid & 7) * 128 + (bid >> 3);
    const int q0  = (swz & 31) * QT;
    const int bh  = swz >> 5;

    const size_t base = (size_t)bh * Lq * E_;
    const float* Qp = Q + base;
    const float* Kp = K + base;
    const float* Vp = V + base;
    float*       Op = O + base;

    const int qb = q0 + w * 16;    // this wave's q rows: qb..qb+15

    // ---- Q fragments in registers (scale * log2e folded in) ----
    FragU qf[4];
    {
        const float* qrow = Qp + (size_t)(qb + c) * E_ + g * 8;
        #pragma unroll
        for (int ck = 0; ck < 4; ++ck) {
            #pragma unroll
            for (int j = 0; j < 8; ++j)
                qf[ck].s[j] = f2bf(qrow[ck * 32 + j] * SCALE_LOG2E);
        }
    }

    f32x4 acc[8];
    #pragma unroll
    for (int n = 0; n < 8; ++n) acc[n] = (f32x4){0.f, 0.f, 0.f, 0.f};
    float m_r[4], l_r[4];
    #pragma unroll
    for (int r = 0; r < 4; ++r) { m_r[r] = -1e30f; l_r[r] = 0.f; }

    const int kv_lo = (q0 - WIN) > 0 ? (q0 - WIN) : 0;
    const int kv_hi = q0 + QT;     // exclusive

    // ---- reg-double-buffered staging ----
    float4 kr[4], vr[4];

    auto issue_loads = [&](int kt) {
        const float4* K4 = reinterpret_cast<const float4*>(Kp + (size_t)kt * E_);
        const float4* V4 = reinterpret_cast<const float4*>(Vp + (size_t)kt * E_);
        #pragma unroll
        for (int i = 0; i < 4; ++i) {
            kr[i] = K4[i * 256 + tid];
            vr[i] = V4[i * 256 + tid];
        }
    };
    auto write_lds = [&]() {
        #pragma unroll
        for (int i = 0; i < 4; ++i) {
            int fi  = i * 256 + tid;
            int row = fi >> 5;
            int col = (fi & 31) << 2;
            ushort4 ku;
            ku.x = f2bf(kr[i].x); ku.y = f2bf(kr[i].y);
            ku.z = f2bf(kr[i].z); ku.w = f2bf(kr[i].w);
            *reinterpret_cast<ushort4*>(&sK[row * KSTR + (col ^ ((row & 7) * 8))]) = ku;
            ushort2 va_, vb_;
            va_.x = f2bf(vr[i].x); va_.y = f2bf(vr[i].y);
            vb_.x = f2bf(vr[i].z); vb_.y = f2bf(vr[i].w);
            *reinterpret_cast<ushort2*>(&sV[row * VSTR + col])     = va_;
            *reinterpret_cast<ushort2*>(&sV[row * VSTR + col + 2]) = vb_;
        }
    };

    issue_loads(kv_lo);
    write_lds();
    __syncthreads();

    for (int kt = kv_lo; kt < kv_hi; kt += KT) {
        const bool more = (kt + KT) < kv_hi;
        if (more) issue_loads(kt + KT);   // in flight during compute

        // ---- S = Q K^T : two 16-key sub-tiles, K-dim 128 = 4 chunks ----
        f32x4 s0 = {0.f,0.f,0.f,0.f}, s1 = {0.f,0.f,0.f,0.f};
        #pragma unroll
        for (int ck = 0; ck < 4; ++ck) {
            int r0 = c;
            int r1 = 16 + c;
            int cb = ck * 32 + g * 8;
            bf16x8 k0 = *reinterpret_cast<const bf16x8*>(&sK[r0 * KSTR + (cb ^ ((r0 & 7) * 8))]);
            bf16x8 k1 = *reinterpret_cast<const bf16x8*>(&sK[r1 * KSTR + (cb ^ ((r1 & 7) * 8))]);
            s0 = __builtin_amdgcn_mfma_f32_16x16x32_bf16(qf[ck].v, k0, s0, 0, 0, 0);
            s1 = __builtin_amdgcn_mfma_f32_16x16x32_bf16(qf[ck].v, k1, s1, 0, 0, 0);
        }

        // ---- mask (causal + window), wave-uniform skip for interior tiles ----
        bool need_mask = (kt + KT - 1 > qb) || ((qb + 15) - kt > WIN);
        if (need_mask) {
            #pragma unroll
            for (int r = 0; r < 4; ++r) {
                int qi  = qb + g * 4 + r;
                int k0i = kt + c;
                int k1i = kt + 16 + c;
                if (k0i > qi || qi - k0i > WIN) s0[r] = -1e30f;
                if (k1i > qi || qi - k1i > WIN) s1[r] = -1e30f;
            }
        }

        // ---- online softmax (exp2 domain; scale already folded into Q) ----
        #pragma unroll
        for (int r = 0; r < 4; ++r) {
            float t = fmaxf(s0[r], s1[r]);
            #pragma unroll
            for (int off = 1; off < 16; off <<= 1)
                t = fmaxf(t, __shfl_xor(t, off, 16));
            float mnew = fmaxf(m_r[r], t);
            float fac  = exp2f(m_r[r] - mnew);
            float p0   = exp2f(s0[r] - mnew);
            float p1   = exp2f(s1[r] - mnew);
            float rs = p0 + p1;
            #pragma unroll
            for (int off = 1; off < 16; off <<= 1)
                rs += __shfl_xor(rs, off, 16);
            l_r[r] = l_r[r] * fac + rs;
            m_r[r] = mnew;
            #pragma unroll
            for (int n = 0; n < 8; ++n) acc[n][r] *= fac;
            sP[(w * 16 + g * 4 + r) * PSTR + c]      = f2bf(p0);
            sP[(w * 16 + g * 4 + r) * PSTR + 16 + c] = f2bf(p1);
        }

        // ---- PV: A = P (b128 from per-wave LDS), B = V (scalar gathers) ----
        // per-wave P buffer: in-wave DS ordering guarantees write->read
        bf16x8 pa = *reinterpret_cast<const bf16x8*>(&sP[(w * 16 + c) * PSTR + g * 8]);
        #pragma unroll
        for (int n = 0; n < 8; ++n) {
            FragU vf;
            #pragma unroll
            for (int j = 0; j < 8; ++j)
                vf.s[j] = sV[(g * 8 + j) * VSTR + n * 16 + c];
            acc[n] = __builtin_amdgcn_mfma_f32_16x16x32_bf16(pa, vf.v, acc[n], 0, 0, 0);
        }

        __syncthreads();            // everyone done reading tile kt
        if (more) write_lds();      // vmcnt waits inserted by compiler
        __syncthreads();            // tile kt+KT ready
    }

    // ---- epilogue: divide by l, store fp32 ----
    #pragma unroll
    for (int r = 0; r < 4; ++r) {
        float inv = 1.0f / l_r[r];
        int qi = qb + g * 4 + r;
        #pragma unroll
        for (int n = 0; n < 8; ++n)
            Op[(size_t)qi * E_ + n * 16 + c] = acc[n][r] * inv;
    }
}

extern "C" void kernel_launch(void* const* d_in, const int* in_sizes, int n_in,
                              void* d_out, int out_size, void* d_ws, size_t ws_size,
                              hipStream_t stream) {
    (void)in_sizes; (void)n_in; (void)out_size; (void)d_ws; (void)ws_size;
    const float* q = (const float*)d_in[0];
    const float* k = (const float*)d_in[1];
    const float* v = (const float*)d_in[2];
    float* o = (float*)d_out;
    dim3 grid((Lq / QT) * (B_ * H_));
    hipLaunchKernelGGL(flexattn_kernel, grid, dim3(256), 0, stream, q, k, v, o);
}

// Round 8
// 200.930 us; speedup vs baseline: 1.2960x; 1.2960x over previous
//
#include <hip/hip_runtime.h>

// FlexAttention: sliding-window (512) causal attention.
// B=2, H=16, L=2048, E=128, fp32 in/out, bf16 MFMA compute, fp32 accum.
// R7 (resubmit; infra failure): revert reg-dbuf + XCD swizzle (R6 regressed
// 152->168us; latency was never in global loads). Attack the per-tile serial
// chain instead:
//  - softmax max/sum reductions via DPP (VALU) instead of __shfl_xor (DS pipe)
//  - HW bf16 casts (v_cvt_pk_bf16_f32) instead of 4-op software RNE

typedef __bf16 bf16_t;
typedef bf16_t bf16x8 __attribute__((ext_vector_type(8)));
typedef float f32x4 __attribute__((ext_vector_type(4)));

union FragU { bf16x8 v; unsigned short s[8]; bf16_t b[8]; };
union BF4 { ushort4 u4; ushort2 u2[2]; bf16_t b[4]; };

constexpr int B_ = 2, H_ = 16, Lq = 2048, E_ = 128, WIN = 512;
constexpr int QT = 64;     // q rows per block (4 waves x 16)
constexpr int KT = 32;     // keys per kv tile
constexpr int KSTR = 128;  // sK row stride (u16); XOR-swizzled within row
constexpr int VSTR = 130;  // sV row stride (u16)
constexpr int PSTR = 40;   // sP row stride (u16)

// (1/sqrt(128)) * log2(e); softmax done in exp2 domain
#define SCALE_LOG2E 0.1275174364f

// 16-lane (DPP row) butterfly step: permute within the row, no DS traffic.
template<int CTRL>
__device__ __forceinline__ float fdpp(float x) {
    int i = __builtin_bit_cast(int, x);
    int r = __builtin_amdgcn_update_dpp(i, i, CTRL, 0xF, 0xF, false);
    return __builtin_bit_cast(float, r);
}
// full 16-lane reduction: xor1 (quad_perm), xor2 (quad_perm),
// 8-group partner (row_half_mirror), 16-group partner (row_mirror)
__device__ __forceinline__ float rowmax16(float t) {
    t = fmaxf(t, fdpp<0xB1>(t));
    t = fmaxf(t, fdpp<0x4E>(t));
    t = fmaxf(t, fdpp<0x141>(t));
    t = fmaxf(t, fdpp<0x140>(t));
    return t;
}
__device__ __forceinline__ float rowsum16(float t) {
    t += fdpp<0xB1>(t);
    t += fdpp<0x4E>(t);
    t += fdpp<0x141>(t);
    t += fdpp<0x140>(t);
    return t;
}

extern "C" __global__ __launch_bounds__(256, 2)
void flexattn_kernel(const float* __restrict__ Q,
                     const float* __restrict__ K,
                     const float* __restrict__ V,
                     float* __restrict__ O)
{
    __shared__ unsigned short sK[KT * KSTR];   // row-major, XOR-swizzled
    __shared__ unsigned short sV[KT * VSTR];   // row-major, padded stride
    __shared__ unsigned short sP[4 * 16 * PSTR];

    const int tid  = threadIdx.x;
    const int w    = tid >> 6;     // wave 0..3
    const int lane = tid & 63;
    const int c    = lane & 15;    // col within MFMA tile
    const int g    = lane >> 4;    // 16-lane group 0..3

    const int q0 = blockIdx.x * QT;
    const int bh = blockIdx.y;
    const size_t base = (size_t)bh * Lq * E_;
    const float* Qp = Q + base;
    const float* Kp = K + base;
    const float* Vp = V + base;
    float*       Op = O + base;

    const int qb = q0 + w * 16;    // this wave's q rows: qb..qb+15

    // ---- Q fragments in registers (scale * log2e folded in) ----
    FragU qf[4];
    {
        const float* qrow = Qp + (size_t)(qb + c) * E_ + g * 8;
        #pragma unroll
        for (int ck = 0; ck < 4; ++ck) {
            #pragma unroll
            for (int j = 0; j < 8; ++j)
                qf[ck].b[j] = (bf16_t)(qrow[ck * 32 + j] * SCALE_LOG2E);
        }
    }

    f32x4 acc[8];
    #pragma unroll
    for (int n = 0; n < 8; ++n) acc[n] = (f32x4){0.f, 0.f, 0.f, 0.f};
    float m_r[4], l_r[4];
    #pragma unroll
    for (int r = 0; r < 4; ++r) { m_r[r] = -1e30f; l_r[r] = 0.f; }

    const int kv_lo = (q0 - WIN) > 0 ? (q0 - WIN) : 0;
    const int kv_hi = q0 + QT;     // exclusive

    for (int kt = kv_lo; kt < kv_hi; kt += KT) {
        __syncthreads();
        // ---- stage K,V tile (32x128 fp32 -> bf16 LDS), coalesced float4 ----
        #pragma unroll
        for (int i = 0; i < 4; ++i) {
            int fi  = i * 256 + tid;        // float4 index within tile
            int row = fi >> 5;
            int col = (fi & 31) << 2;
            float4 kx = reinterpret_cast<const float4*>(Kp + (size_t)kt * E_)[fi];
            float4 vx = reinterpret_cast<const float4*>(Vp + (size_t)kt * E_)[fi];
            BF4 ku;
            ku.b[0] = (bf16_t)kx.x; ku.b[1] = (bf16_t)kx.y;
            ku.b[2] = (bf16_t)kx.z; ku.b[3] = (bf16_t)kx.w;
            *reinterpret_cast<ushort4*>(&sK[row * KSTR + (col ^ ((row & 7) * 8))]) = ku.u4;
            BF4 vu;
            vu.b[0] = (bf16_t)vx.x; vu.b[1] = (bf16_t)vx.y;
            vu.b[2] = (bf16_t)vx.z; vu.b[3] = (bf16_t)vx.w;
            *reinterpret_cast<ushort2*>(&sV[row * VSTR + col])     = vu.u2[0];
            *reinterpret_cast<ushort2*>(&sV[row * VSTR + col + 2]) = vu.u2[1];
        }
        __syncthreads();

        // ---- S = Q K^T : two 16-key sub-tiles, K-dim 128 = 4 chunks ----
        f32x4 s0 = {0.f,0.f,0.f,0.f}, s1 = {0.f,0.f,0.f,0.f};
        #pragma unroll
        for (int ck = 0; ck < 4; ++ck) {
            int r0 = c;
            int r1 = 16 + c;
            int cb = ck * 32 + g * 8;
            bf16x8 k0 = *reinterpret_cast<const bf16x8*>(&sK[r0 * KSTR + (cb ^ ((r0 & 7) * 8))]);
            bf16x8 k1 = *reinterpret_cast<const bf16x8*>(&sK[r1 * KSTR + (cb ^ ((r1 & 7) * 8))]);
            s0 = __builtin_amdgcn_mfma_f32_16x16x32_bf16(qf[ck].v, k0, s0, 0, 0, 0);
            s1 = __builtin_amdgcn_mfma_f32_16x16x32_bf16(qf[ck].v, k1, s1, 0, 0, 0);
        }

        // ---- mask (causal + window), wave-uniform skip for interior tiles ----
        bool need_mask = (kt + KT - 1 > qb) || ((qb + 15) - kt > WIN);
        if (need_mask) {
            #pragma unroll
            for (int r = 0; r < 4; ++r) {
                int qi  = qb + g * 4 + r;
                int k0i = kt + c;
                int k1i = kt + 16 + c;
                if (k0i > qi || qi - k0i > WIN) s0[r] = -1e30f;
                if (k1i > qi || qi - k1i > WIN) s1[r] = -1e30f;
            }
        }

        // ---- online softmax (exp2 domain; DPP reductions, no DS traffic) ----
        #pragma unroll
        for (int r = 0; r < 4; ++r) {
            float t = rowmax16(fmaxf(s0[r], s1[r]));
            float mnew = fmaxf(m_r[r], t);
            float fac  = exp2f(m_r[r] - mnew);
            float p0   = exp2f(s0[r] - mnew);
            float p1   = exp2f(s1[r] - mnew);
            float rs   = rowsum16(p0 + p1);
            l_r[r] = l_r[r] * fac + rs;
            m_r[r] = mnew;
            #pragma unroll
            for (int n = 0; n < 8; ++n) acc[n][r] *= fac;
            sP[(w * 16 + g * 4 + r) * PSTR + c] =
                __builtin_bit_cast(unsigned short, (bf16_t)p0);
            sP[(w * 16 + g * 4 + r) * PSTR + 16 + c] =
                __builtin_bit_cast(unsigned short, (bf16_t)p1);
        }

        // ---- PV: A = P (b128 from per-wave LDS), B = V (scalar gathers) ----
        // per-wave P buffer: in-wave DS ordering guarantees write->read
        bf16x8 pa = *reinterpret_cast<const bf16x8*>(&sP[(w * 16 + c) * PSTR + g * 8]);
        #pragma unroll
        for (int n = 0; n < 8; ++n) {
            FragU vf;
            #pragma unroll
            for (int j = 0; j < 8; ++j)
                vf.s[j] = sV[(g * 8 + j) * VSTR + n * 16 + c];
            acc[n] = __builtin_amdgcn_mfma_f32_16x16x32_bf16(pa, vf.v, acc[n], 0, 0, 0);
        }
    }

    // ---- epilogue: divide by l, store fp32 ----
    #pragma unroll
    for (int r = 0; r < 4; ++r) {
        float inv = 1.0f / l_r[r];
        int qi = qb + g * 4 + r;
        #pragma unroll
        for (int n = 0; n < 8; ++n)
            Op[(size_t)qi * E_ + n * 16 + c] = acc[n][r] * inv;
    }
}

extern "C" void kernel_launch(void* const* d_in, const int* in_sizes, int n_in,
                              void* d_out, int out_size, void* d_ws, size_t ws_size,
                              hipStream_t stream) {
    (void)in_sizes; (void)n_in; (void)out_size; (void)d_ws; (void)ws_size;
    const float* q = (const float*)d_in[0];
    const float* k = (const float*)d_in[1];
    const float* v = (const float*)d_in[2];
    float* o = (float*)d_out;
    dim3 grid(Lq / QT, B_ * H_);
    hipLaunchKernelGGL(flexattn_kernel, grid, dim3(256), 0, stream, q, k, v, o);
}